// Round 9
// baseline (9474.348 us; speedup 1.0000x reference)
//
#include <hip/hip_runtime.h>
#include <math.h>

// ---------------------------------------------------------------------------
// MDN-RNN round 9: r7 base (6.0 ms) with the compute core restructured.
//  - Waves 0-3 each own ONE row-tile (4 units x 4 gates = 16 MFMA rows) and
//    run all three hi/lo passes as 3 independent MFMA chains (accA/accB/accC).
//    After MFMA, each lane's C-frag regs hold ALL 4 gates of its
//    (unit = u0+wave*4+(lane>>4), batch = b0+(lane&15)) -> pointwise + c
//    update + h-store fully in-register. E phase and gC LDS round trip GONE.
//  - Waves 4-7: L1 (lane-paired k-halves, shfl_xor combine -> hid1L[parC]).
//  - 3 barriers/step: syncA (poll/head) | syncB (stage) | syncC (h stores
//    drained) -> flag publish.
//  - A/B phases, 16-thread dedicated pollers, packed-u32 h exchange: r7
//    verbatim (proven 6.0 ms / absmax 0.0083).
// Lags: L1@s: h_s | L2: h_{s-1} | L3: h_{s-2} | FIN -> t = s-4. s = 0..1026.
// ---------------------------------------------------------------------------

#define NOUT 1023
#define KK   5
#define MEANBASE (256 * NOUT * KK)
#define VARBASE  (MEANBASE + 256 * NOUT * KK * 32)

// ws layout
#define OFF_HB   0            // u32[2][256][256] h ping-pong (lo<<16|hi bf16)
#define OFF_FLG  131072       // float-idx of 256 uint flags
#define OFF_W1T  131136       // fp32 [256k][128ch]
#define OFF_W2T  163904       // fp32 [100k][128ch]
#define OFF_W3T  176704       // fp32 [100k][192ch]

typedef __attribute__((ext_vector_type(8))) short s8t;
typedef __attribute__((ext_vector_type(4))) float f4t;

__device__ __forceinline__ float sigf(float v) { return 1.0f / (1.0f + expf(-v)); }
__device__ __forceinline__ unsigned short f2bf(float f) {
    unsigned u = __float_as_uint(f);
    u += 0x7fffu + ((u >> 16) & 1u);
    return (unsigned short)(u >> 16);
}
__device__ __forceinline__ float bf2f(unsigned short h) {
    return __uint_as_float(((unsigned)h) << 16);
}

// ------------------- one-time: transposed head weights ----------------------
__global__ __launch_bounds__(256) void prep_pack(
    const float* __restrict__ W1, const float* __restrict__ W2,
    const float* __restrict__ W3, float* __restrict__ ws)
{
    const int idx = blockIdx.x * 256 + threadIdx.x;
    if (idx < 32768) {                       // W1T[k 256][128]
        int k = idx >> 7, c = idx & 127;
        if (c < 100) ws[OFF_W1T + idx] = W1[c * 256 + k];
    } else if (idx < 45568) {                // W2T[k 100][128]
        int r = idx - 32768;
        int k = r >> 7, c = r & 127;
        if (c < 100) ws[OFF_W2T + r] = W2[c * 100 + k];
    } else if (idx < 64768) {                // W3T[k 100][192]
        int r = idx - 45568;
        int k = r / 192, c = r - k * 192;
        if (c < 170) ws[OFF_W3T + r] = W3[c * 100 + k];
    }
}

// ------------------------------ persistent kernel ---------------------------
__global__ __launch_bounds__(512, 1) void mdn_rnn_persist(
    const float* __restrict__ x,
    const float* __restrict__ W_ih, const float* __restrict__ W_hh,
    const float* __restrict__ b_ih, const float* __restrict__ b_hh,
    const float* __restrict__ b1, const float* __restrict__ b2,
    const float* __restrict__ b3,
    float* __restrict__ ws, float* __restrict__ out)
{
    __shared__ __align__(16) unsigned short hFhi[4096], hFlo[4096]; // [sk8][kg4][n16][j8]
    __shared__ __align__(16) unsigned short xFh[1024], xFl[1024];
    __shared__ __align__(16) float hcolL[256];
    __shared__ float hid1L[2][104], hid2L[2][104], oL[2][176];
    __shared__ float xst[2][704];                    // [j35][b16 pad20]

    const int tid  = threadIdx.x;
    const int wg   = blockIdx.x;
    const int ut   = wg >> 4;
    const int g    = wg & 15;
    const int u0   = ut * 16;
    const int b0   = g * 16;
    const int bhead = b0 + ut;
    const int wave = tid >> 6;
    const int lane = tid & 63;

    unsigned* hb = (unsigned*)ws;                    // OFF_HB
    unsigned* flags = (unsigned*)(ws + OFF_FLG);

    // x prefetch mapping (tid < 280, 2 elems each of 16b x 35j)
    const int e0 = tid * 2, pb0 = e0 / 35, pj0 = e0 - pb0 * 35;
    const int e1 = e0 + 1,  pb1 = e1 / 35, pj1 = e1 - pb1 * 35;

    // ---- A-fragments (registers, persistent). Waves 0-3: tile = wave. ----
    s8t aWhi[8], aWlo[8], aXh[2], aXl[2];
    f4t breg = (f4t){0.f, 0.f, 0.f, 0.f};
    float b1r = 0.f;
    if (wave < 4) {
        const int m = lane & 15;
        const int usub = m >> 2, gate = m & 3;
        const int kb8 = (lane >> 4) * 8;
        const size_t rowh = (size_t)(gate * 256 + u0 + wave * 4 + usub) * 256;
        const size_t rowx = (size_t)(gate * 256 + u0 + wave * 4 + usub) * 35;
        #pragma unroll
        for (int sk = 0; sk < 8; ++sk) {
            s8t vh, vl;
            #pragma unroll
            for (int j = 0; j < 8; ++j) {
                float wv = W_hh[rowh + sk * 32 + kb8 + j];
                unsigned short hi = f2bf(wv);
                vh[j] = (short)hi;
                vl[j] = (short)f2bf(wv - bf2f(hi));
            }
            aWhi[sk] = vh; aWlo[sk] = vl;
        }
        #pragma unroll
        for (int sk = 0; sk < 2; ++sk) {
            s8t vh, vl;
            #pragma unroll
            for (int j = 0; j < 8; ++j) {
                int k = sk * 32 + kb8 + j;
                float wv = (k < 35) ? W_ih[rowx + k] : 0.f;
                unsigned short hi = f2bf(wv);
                vh[j] = (short)hi;
                vl[j] = (short)f2bf(wv - bf2f(hi));
            }
            aXh[sk] = vh; aXl[sk] = vl;
        }
        const int unit = u0 + wave * 4 + (lane >> 4);
        breg = (f4t){ b_ih[unit]       + b_hh[unit],
                      b_ih[256 + unit] + b_hh[256 + unit],
                      b_ih[512 + unit] + b_hh[512 + unit],
                      b_ih[768 + unit] + b_hh[768 + unit] };
    } else {
        #pragma unroll
        for (int i = 0; i < 8; ++i) { aWhi[i] = (s8t)0; aWlo[i] = (s8t)0; }
        aXh[0] = aXh[1] = aXl[0] = aXl[1] = (s8t)0;
        const int ch = (tid - 256) >> 1;
        if (ch < 100) b1r = b1[ch];
    }
    // prologue: x_0 -> xst[0]
    if (tid < 280) {
        xst[0][pj0 * 20 + pb0] = x[(size_t)(b0 + pb0) * 35840 + pj0];
        xst[0][pj1 * 20 + pb1] = x[(size_t)(b0 + pb1) * 35840 + pj1];
    }
    __syncthreads();

    float c_reg = 0.0f;

    for (int s = 0; s < 1027; ++s) {
        const int parC = s & 1;
        const int parN = parC ^ 1;

        // ============ A: head roles + dedicated pollers (r7) ===============
        float xpf0 = 0.f, xpf1 = 0.f;
        const bool dopf = (s < 1022) && (tid < 280);
        if (dopf) {
            const float* xp = x + (size_t)(s + 1) * 35;
            xpf0 = __builtin_nontemporal_load(xp + (size_t)(b0 + pb0) * 35840 + pj0);
            xpf1 = __builtin_nontemporal_load(xp + (size_t)(b0 + pb1) * 35840 + pj1);
        }
        if (tid < 100) {                                   // L2: hid2(h_{s-1})
            if (s >= 2 && s <= 1024) {
                const float* W2T = ws + OFF_W2T;
                float a0 = 0.f, a1 = 0.f;
                #pragma unroll 10
                for (int k = 0; k < 50; ++k) {
                    a0 = fmaf(W2T[k * 128 + tid],        hid1L[parN][k],      a0);
                    a1 = fmaf(W2T[(k + 50) * 128 + tid], hid1L[parN][k + 50], a1);
                }
                hid2L[parC][tid] = fmaxf(a0 + a1 + b2[tid], 0.f);
            }
        } else if (tid >= 128 && tid < 298) {              // L3: o(h_{s-2})
            if (s >= 3 && s <= 1025) {
                const int ch = tid - 128;
                const float* W3T = ws + OFF_W3T;
                float a0 = 0.f, a1 = 0.f;
                #pragma unroll 10
                for (int k = 0; k < 50; ++k) {
                    a0 = fmaf(W3T[k * 192 + ch],        hid2L[parN][k],      a0);
                    a1 = fmaf(W3T[(k + 50) * 192 + ch], hid2L[parN][k + 50], a1);
                }
                oL[parC][ch] = a0 + a1 + b3[ch];
            }
        } else if (tid >= 320 && tid < 490) {              // FIN: t = s-4
            if (s >= 4) {
                const int ch = tid - 320;
                const int t  = s - 4;
                float m5 = oL[parN][0];
                #pragma unroll
                for (int k = 1; k < KK; ++k) m5 = fmaxf(m5, oL[parN][k]);
                float den = 0.f;
                #pragma unroll
                for (int k = 0; k < KK; ++k) den += expf(oL[parN][k] - m5);
                float v = oL[parN][ch];
                if (ch < KK)
                    out[(size_t)bhead * 5115 + (size_t)t * 5 + ch] = expf(v - m5) / den;
                else if (ch < 2 * KK)
                    out[VARBASE + (size_t)bhead * 5115 + (size_t)t * 5 + (ch - 5)] = expf(v);
                else
                    out[MEANBASE + ((size_t)bhead * NOUT + t) * 160 + (ch - 10)] = v;
            }
        } else if (tid >= 490 && tid < 506) {              // poll cluster flags
            if (s >= 1 && s <= 1023) {
                const unsigned tgt = (unsigned)s;
                while (__hip_atomic_load(&flags[g * 16 + (tid - 490)],
                                         __ATOMIC_RELAXED,
                                         __HIP_MEMORY_SCOPE_AGENT) < tgt)
                    __builtin_amdgcn_s_sleep(1);
            }
        }
        __syncthreads();  // syncA

        // ============ B: stage h_s -> frag LDS + hcol + x frags (r7) =======
        if (s <= 1023) {
            const int sk = tid >> 6, kg = (tid >> 4) & 3, n = tid & 15;
            const unsigned* src = hb + parC * 65536 + (sk * 32 + kg * 8) * 256 + b0 + n;
            unsigned v[8];
            #pragma unroll
            for (int j = 0; j < 8; ++j)
                v[j] = __hip_atomic_load(src + j * 256, __ATOMIC_RELAXED,
                                         __HIP_MEMORY_SCOPE_AGENT);
            s8t h8, l8;
            float fc[8];
            #pragma unroll
            for (int j = 0; j < 8; ++j) {
                unsigned short hi = (unsigned short)(v[j] & 0xffffu);
                unsigned short lo = (unsigned short)(v[j] >> 16);
                h8[j] = (short)hi; l8[j] = (short)lo;
                fc[j] = bf2f(hi) + bf2f(lo);
            }
            *(s8t*)&hFhi[sk * 512 + kg * 128 + n * 8] = h8;
            *(s8t*)&hFlo[sk * 512 + kg * 128 + n * 8] = l8;
            if (n == ut) {
                #pragma unroll
                for (int j = 0; j < 8; ++j) hcolL[sk * 32 + kg * 8 + j] = fc[j];
            }
            if (tid < 128) {                               // x frags
                const int sk2 = tid >> 6;
                s8t xh8, xl8;
                #pragma unroll
                for (int j = 0; j < 8; ++j) {
                    int k = sk2 * 32 + kg * 8 + j;
                    float xv = (k < 35) ? xst[parC][k * 20 + n] : 0.f;
                    unsigned short hi = f2bf(xv);
                    xh8[j] = (short)hi;
                    xl8[j] = (short)f2bf(xv - bf2f(hi));
                }
                *(s8t*)&xFh[sk2 * 512 + kg * 128 + n * 8] = xh8;
                *(s8t*)&xFl[sk2 * 512 + kg * 128 + n * 8] = xl8;
            }
        }
        if (dopf) {                                        // x_{s+1} -> xst[parN]
            xst[parN][pj0 * 20 + pb0] = xpf0;
            xst[parN][pj1 * 20 + pb1] = xpf1;
        }
        __syncthreads();  // syncB

        // ============ C: MFMA + in-register pointwise | L1 =================
        if (wave < 4) {
            if (s <= 1022) {
                f4t accA = (f4t){0.f, 0.f, 0.f, 0.f};
                f4t accB = accA, accC = accA;
                const int fo = lane * 8;
                #pragma unroll
                for (int sk = 0; sk < 8; ++sk) {
                    s8t bh = *(const s8t*)&hFhi[sk * 512 + fo];
                    s8t bl = *(const s8t*)&hFlo[sk * 512 + fo];
                    accA = __builtin_amdgcn_mfma_f32_16x16x32_bf16(aWhi[sk], bh, accA, 0, 0, 0);
                    accB = __builtin_amdgcn_mfma_f32_16x16x32_bf16(aWhi[sk], bl, accB, 0, 0, 0);
                    accC = __builtin_amdgcn_mfma_f32_16x16x32_bf16(aWlo[sk], bh, accC, 0, 0, 0);
                }
                #pragma unroll
                for (int sk = 0; sk < 2; ++sk) {
                    s8t xh = *(const s8t*)&xFh[sk * 512 + fo];
                    s8t xl = *(const s8t*)&xFl[sk * 512 + fo];
                    accA = __builtin_amdgcn_mfma_f32_16x16x32_bf16(aXh[sk], xh, accA, 0, 0, 0);
                    accB = __builtin_amdgcn_mfma_f32_16x16x32_bf16(aXh[sk], xl, accB, 0, 0, 0);
                    accC = __builtin_amdgcn_mfma_f32_16x16x32_bf16(aXl[sk], xh, accC, 0, 0, 0);
                }
                // pointwise in-register: lane owns (unit, batch), regs = gates
                float gi  = accA.x + accB.x + accC.x + breg.x;
                float gf  = accA.y + accB.y + accC.y + breg.y;
                float gg_ = accA.z + accB.z + accC.z + breg.z;
                float go  = accA.w + accB.w + accC.w + breg.w;
                float iv = sigf(gi), fv = sigf(gf);
                float gv = tanhf(gg_), ov = sigf(go);
                c_reg = fv * c_reg + iv * gv;
                float hval = ov * tanhf(c_reg);
                unsigned hi16 = f2bf(hval);
                unsigned lo16 = f2bf(hval - bf2f((unsigned short)hi16));
                unsigned pk = (lo16 << 16) | hi16;
                const int unit = u0 + wave * 4 + (lane >> 4);
                __hip_atomic_store(hb + parN * 65536 + unit * 256 + b0 + (lane & 15),
                                   pk, __ATOMIC_RELAXED, __HIP_MEMORY_SCOPE_AGENT);
            }
        } else {                                           // L1: hid1(h_s)
            const int r = tid - 256, ch = r >> 1, kh = r & 1;
            if (s >= 1 && s <= 1023 && ch < 100) {
                const int kb = kh * 128;
                const float* Wp = ws + OFF_W1T + ch;
                float s0 = 0.f, s1 = 0.f;
                #pragma unroll 16
                for (int i = 0; i < 64; ++i) {
                    s0 = fmaf(Wp[(kb + i) * 128],      hcolL[kb + i],      s0);
                    s1 = fmaf(Wp[(kb + 64 + i) * 128], hcolL[kb + 64 + i], s1);
                }
                float v = s0 + s1;
                float pv = __shfl_xor(v, 1);
                if (kh == 0)
                    hid1L[parC][ch] = fmaxf(v + pv + b1r, 0.f);
            }
        }
        __syncthreads();  // syncC: drains vmcnt -> h stores complete
        if (s <= 1022 && tid == 0)
            __hip_atomic_store(&flags[g * 16 + ut], (unsigned)(s + 1),
                               __ATOMIC_RELAXED, __HIP_MEMORY_SCOPE_AGENT);
    }
}

extern "C" void kernel_launch(void* const* d_in, const int* in_sizes, int n_in,
                              void* d_out, int out_size, void* d_ws, size_t ws_size,
                              hipStream_t stream)
{
    const float* x    = (const float*)d_in[0];
    const float* W_ih = (const float*)d_in[1];
    const float* W_hh = (const float*)d_in[2];
    const float* b_ih = (const float*)d_in[3];
    const float* b_hh = (const float*)d_in[4];
    const float* W1   = (const float*)d_in[5];
    const float* b1   = (const float*)d_in[6];
    const float* W2   = (const float*)d_in[7];
    const float* b2   = (const float*)d_in[8];
    const float* W3   = (const float*)d_in[9];
    const float* b3   = (const float*)d_in[10];
    float* out = (float*)d_out;
    float* ws  = (float*)d_ws;

    hipMemsetAsync(ws, 0, 65536 * sizeof(unsigned), stream);          // h_0 = 0
    hipMemsetAsync(ws + OFF_FLG, 0, 256 * sizeof(unsigned), stream);  // flags
    prep_pack<<<254, 256, 0, stream>>>(W1, W2, W3, ws);
    mdn_rnn_persist<<<256, 512, 0, stream>>>(x, W_ih, W_hh, b_ih, b_hh,
                                             b1, b2, b3, ws, out);
}